// Round 2
// baseline (5301.004 us; speedup 1.0000x reference)
//
#include <hip/hip_runtime.h>
#include <math.h>

#define HN 16
#define SEQ 1024
#define DMODEL 1024
#define DH 64
#define SM1 1023   // S-1

// ---------------------------------------------------------------
// Kernel A/D: fp32 GEMM  out = X @ W + bias
// MODE 0: head-split output  out[((b*HN+h)*rows + s)*64 + dh]
// MODE 1: plain output       out[m*1024 + n]
// BM=BN=64, BK=16, 256 threads, 4x4 per thread.
// ---------------------------------------------------------------
template<int MODE>
__global__ __launch_bounds__(256)
void gemm64_kernel(const float* __restrict__ X, const float* __restrict__ W,
                   const float* __restrict__ bias, float* __restrict__ out,
                   int M, int rows)
{
    __shared__ __align__(16) float As[16][68];
    __shared__ __align__(16) float Bs[16][68];
    const int t  = threadIdx.x;
    const int tx = t & 15, ty = t >> 4;
    const int m0 = blockIdx.y * 64, n0 = blockIdx.x * 64;
    const int arow = t >> 2, aq = t & 3;
    const int brow = t >> 4, bq4 = t & 15;

    float acc[4][4] = {};

    for (int k0 = 0; k0 < DMODEL; k0 += 16) {
        __syncthreads();
        float4 av = {0.f, 0.f, 0.f, 0.f};
        if (m0 + arow < M)
            av = *(const float4*)&X[(size_t)(m0 + arow) * DMODEL + k0 + aq * 4];
        As[aq * 4 + 0][arow] = av.x;
        As[aq * 4 + 1][arow] = av.y;
        As[aq * 4 + 2][arow] = av.z;
        As[aq * 4 + 3][arow] = av.w;
        float4 bv = *(const float4*)&W[(size_t)(k0 + brow) * DMODEL + n0 + bq4 * 4];
        *(float4*)&Bs[brow][bq4 * 4] = bv;
        __syncthreads();

#pragma unroll
        for (int kk = 0; kk < 16; ++kk) {
            float4 a = *(const float4*)&As[kk][ty * 4];
            float4 b = *(const float4*)&Bs[kk][tx * 4];
            acc[0][0] += a.x * b.x; acc[0][1] += a.x * b.y; acc[0][2] += a.x * b.z; acc[0][3] += a.x * b.w;
            acc[1][0] += a.y * b.x; acc[1][1] += a.y * b.y; acc[1][2] += a.y * b.z; acc[1][3] += a.y * b.w;
            acc[2][0] += a.z * b.x; acc[2][1] += a.z * b.y; acc[2][2] += a.z * b.z; acc[2][3] += a.z * b.w;
            acc[3][0] += a.w * b.x; acc[3][1] += a.w * b.y; acc[3][2] += a.w * b.z; acc[3][3] += a.w * b.w;
        }
    }

    float4 b4 = *(const float4*)&bias[n0 + tx * 4];
#pragma unroll
    for (int i = 0; i < 4; ++i) {
        int m = m0 + ty * 4 + i;
        if (m >= M) continue;
        float4 o;
        o.x = acc[i][0] + b4.x; o.y = acc[i][1] + b4.y;
        o.z = acc[i][2] + b4.z; o.w = acc[i][3] + b4.w;
        if (MODE == 0) {
            int bb = m / rows, s = m % rows;
            int h  = n0 >> 6;
            *(float4*)&out[(((size_t)(bb * HN + h) * rows + s) << 6) + tx * 4] = o;
        } else {
            *(float4*)&out[(size_t)m * DMODEL + n0 + tx * 4] = o;
        }
    }
}

// ---------------------------------------------------------------
// Fused attention: QK^T -> relu/scale/mask -> softmax (in regs)
// -> write att weights -> PV -> write ctx.
// Block: 32 q-rows x all 1023 keys, one (b,h). 256 threads.
// Thread (tq=t>>5, tk=t&31) holds logits for rows {tq+8i} x
// keys {tk+32j+128kt}: acc[8][4][4] (128 VGPRs).
// ---------------------------------------------------------------
__global__ __launch_bounds__(256, 2)
void fused_attn_kernel(const float* __restrict__ qh, const float* __restrict__ kh,
                       const float* __restrict__ vh, const int* __restrict__ mask,
                       float* __restrict__ att, float* __restrict__ ctx)
{
    __shared__ __align__(16) float qs[32 * 68];
    __shared__ __align__(16) float ks[128 * 64];   // K (swizzled) then reused for V (linear)
    __shared__ __align__(16) float wtT[128 * 34];  // transposed weight tile [key][row]

    const int b = blockIdx.z, h = blockIdx.y;
    const int q0 = blockIdx.x * 32;
    const int t = threadIdx.x;
    const int tq = t >> 5, tk = t & 31;
    const float* qb = qh + (size_t)(b * HN + h) * SEQ * DH;
    const float* kb = kh + (size_t)(b * HN + h) * SEQ * DH;
    const float* vb = vh + (size_t)(b * HN + h) * SM1 * DH;

    // ---- stage Q (rows q0..q0+31 of att => q rows +1), float4 ----
    for (int p = t; p < 32 * 16; p += 256) {
        int r = p >> 4, d4 = (p & 15) * 4;
        int arow = q0 + r;
        float4 v = {0.f, 0.f, 0.f, 0.f};
        if (arow < SM1) v = *(const float4*)&qb[(size_t)(arow + 1) * DH + d4];
        *(float4*)&qs[r * 68 + d4] = v;
    }

    float acc[8][4][4];

    // ---- QK^T over 8 key tiles of 128 ----
#pragma unroll
    for (int kt = 0; kt < 8; ++kt) {
        const int kstart = kt * 128;
        __syncthreads();
        for (int p = t; p < 128 * 16; p += 256) {
            int r = p >> 4, d4 = (p & 15) * 4;
            int krow = kstart + r;
            float4 v = {0.f, 0.f, 0.f, 0.f};
            if (krow < SM1) v = *(const float4*)&kb[(size_t)krow * DH + d4];
            int s = d4 >> 2;
            *(float4*)&ks[r * 64 + ((s ^ (r & 15)) << 2)] = v;
        }
        __syncthreads();

#pragma unroll
        for (int i = 0; i < 4; ++i)
#pragma unroll
            for (int j = 0; j < 4; ++j)
                acc[kt][i][j] = 0.f;

#pragma unroll
        for (int d0 = 0; d0 < 64; d0 += 4) {
            float4 qv[4], kv[4];
            int s = d0 >> 2;
#pragma unroll
            for (int i = 0; i < 4; ++i)
                qv[i] = *(const float4*)&qs[(tq + 8 * i) * 68 + d0];
#pragma unroll
            for (int j = 0; j < 4; ++j) {
                int r = tk + 32 * j;
                kv[j] = *(const float4*)&ks[r * 64 + ((s ^ (r & 15)) << 2)];
            }
#pragma unroll
            for (int i = 0; i < 4; ++i)
#pragma unroll
                for (int j = 0; j < 4; ++j)
                    acc[kt][i][j] += qv[i].x * kv[j].x + qv[i].y * kv[j].y +
                                     qv[i].z * kv[j].z + qv[i].w * kv[j].w;
        }
    }

    // ---- relu/scale/mask + softmax per row (in regs) + write weights ----
#pragma unroll
    for (int i = 0; i < 4; ++i) {
        const int r = q0 + tq + 8 * i;
        const bool rv = (r < SM1);
        const size_t mbase = ((size_t)b * SM1 + r) * SM1;
        float m = -1e30f;
#pragma unroll
        for (int kt = 0; kt < 8; ++kt)
#pragma unroll
            for (int j = 0; j < 4; ++j) {
                int kk = kt * 128 + tk + 32 * j;
                float sc = -1e30f;
                if (rv && kk < SM1) {
                    sc = fmaxf(acc[kt][i][j] * 0.125f, 0.f);
                    if (mask[mbase + kk]) sc -= 1e9f;
                }
                acc[kt][i][j] = sc;
                m = fmaxf(m, sc);
            }
#pragma unroll
        for (int off = 16; off; off >>= 1) m = fmaxf(m, __shfl_xor(m, off, 64));

        float sum = 0.f;
#pragma unroll
        for (int kt = 0; kt < 8; ++kt)
#pragma unroll
            for (int j = 0; j < 4; ++j) {
                float e = expf(acc[kt][i][j] - m);
                acc[kt][i][j] = e;
                sum += e;
            }
#pragma unroll
        for (int off = 16; off; off >>= 1) sum += __shfl_xor(sum, off, 64);
        const float inv = 1.0f / sum;

        const size_t rbase = ((size_t)(b * HN + h) * SM1 + r) * SM1;
#pragma unroll
        for (int kt = 0; kt < 8; ++kt)
#pragma unroll
            for (int j = 0; j < 4; ++j) {
                int kk = kt * 128 + tk + 32 * j;
                float w = acc[kt][i][j] * inv;
                acc[kt][i][j] = w;
                if (rv && kk < SM1) att[rbase + kk] = w;
            }
    }

    // ---- PV: ctx[rows 2g,2g+1][dh quad d16] ----
    const int g = t >> 4;      // 0..15 -> local rows 2g, 2g+1
    const int d16 = t & 15;    // dh quad
    float4 pacc0 = {0.f, 0.f, 0.f, 0.f};
    float4 pacc1 = {0.f, 0.f, 0.f, 0.f};

#pragma unroll
    for (int kt = 0; kt < 8; ++kt) {
        const int kstart = kt * 128;
        __syncthreads();
        // stage V tile (linear, reuse ks)
        for (int p = t; p < 128 * 16; p += 256) {
            int r = p >> 4, d4 = (p & 15) * 4;
            int krow = kstart + r;
            float4 v = {0.f, 0.f, 0.f, 0.f};
            if (krow < SM1) v = *(const float4*)&vb[(size_t)krow * DH + d4];
            *(float4*)&ks[r * 64 + d4] = v;
        }
        // write transposed weight tile from regs
#pragma unroll
        for (int i = 0; i < 4; ++i)
#pragma unroll
            for (int j = 0; j < 4; ++j)
                wtT[(tk + 32 * j) * 34 + tq + 8 * i] = acc[kt][i][j];
        __syncthreads();

#pragma unroll 8
        for (int k = 0; k < 128; ++k) {
            float2 ww = *(const float2*)&wtT[k * 34 + 2 * g];
            float4 vv = *(const float4*)&ks[k * 64 + d16 * 4];
            pacc0.x += ww.x * vv.x; pacc0.y += ww.x * vv.y;
            pacc0.z += ww.x * vv.z; pacc0.w += ww.x * vv.w;
            pacc1.x += ww.y * vv.x; pacc1.y += ww.y * vv.y;
            pacc1.z += ww.y * vv.z; pacc1.w += ww.y * vv.w;
        }
    }

    const int r0 = q0 + 2 * g;
    if (r0 < SM1)
        *(float4*)&ctx[((size_t)b * SM1 + r0) * DMODEL + h * DH + d16 * 4] = pacc0;
    if (r0 + 1 < SM1)
        *(float4*)&ctx[((size_t)b * SM1 + r0 + 1) * DMODEL + h * DH + d16 * 4] = pacc1;
}

// ---------------------------------------------------------------
extern "C" void kernel_launch(void* const* d_in, const int* in_sizes, int n_in,
                              void* d_out, int out_size, void* d_ws, size_t ws_size,
                              hipStream_t stream) {
    const float* q    = (const float*)d_in[0];
    const float* k    = (const float*)d_in[1];
    const float* v    = (const float*)d_in[2];
    const int*   mask = (const int*)  d_in[4];
    const float* Wq   = (const float*)d_in[5];
    const float* bq   = (const float*)d_in[6];
    const float* Wk   = (const float*)d_in[7];
    const float* bk   = (const float*)d_in[8];
    const float* Wv   = (const float*)d_in[9];
    const float* bv   = (const float*)d_in[10];
    const float* Wo   = (const float*)d_in[11];
    const float* bo   = (const float*)d_in[12];

    float* out0 = (float*)d_out;                       // [2,1023,1024]
    float* att  = out0 + (size_t)2 * SM1 * DMODEL;     // [2,16,1023,1023]

    float* ws  = (float*)d_ws;
    float* qh  = ws;                                   // [2,16,1024,64]
    float* kh  = qh + (size_t)2 * HN * SEQ * DH;       // [2,16,1024,64]
    float* vh  = kh + (size_t)2 * HN * SEQ * DH;       // [2,16,1023,64]
    float* ctx = vh + (size_t)2 * HN * SM1 * DH;       // [2,1023,1024]

    gemm64_kernel<0><<<dim3(16, 32), 256, 0, stream>>>(q, Wq, bq, qh, 2 * SEQ, SEQ);
    gemm64_kernel<0><<<dim3(16, 32), 256, 0, stream>>>(k, Wk, bk, kh, 2 * SEQ, SEQ);
    gemm64_kernel<0><<<dim3(16, 32), 256, 0, stream>>>(v, Wv, bv, vh, 2 * SM1, SM1);

    fused_attn_kernel<<<dim3(32, HN, 2), 256, 0, stream>>>(qh, kh, vh, mask, att, ctx);

    gemm64_kernel<1><<<dim3(16, 32), 256, 0, stream>>>(ctx, Wo, bo, out0, 2 * SM1, SM1);
}

// Round 3
// 515.562 us; speedup vs baseline: 10.2820x; 10.2820x over previous
//
#include <hip/hip_runtime.h>
#include <math.h>

#define HN 16
#define SEQ 1024
#define DMODEL 1024
#define DH 64
#define SM1 1023   // S-1

typedef float  f32x4  __attribute__((ext_vector_type(4)));
typedef __bf16 bf16x8 __attribute__((ext_vector_type(8)));

// ---------------------------------------------------------------
// Kernel A/D: fp32 GEMM  out = X @ W + bias
// MODE 0: head-split bf16 hi/lo planes out[bh][s][64]
// MODE 1: plain fp32 out[m][1024]
// MODE 2: transposed bf16 hi/lo planes out[bh][dh][1024(pad)]
// BM=BN=64, BK=16, 256 threads, 4x4 per thread.
// ---------------------------------------------------------------
template<int MODE>
__global__ __launch_bounds__(256)
void gemm64_kernel(const float* __restrict__ X, const float* __restrict__ W,
                   const float* __restrict__ bias, float* __restrict__ out32,
                   __bf16* __restrict__ outHi, __bf16* __restrict__ outLo,
                   int M, int rows)
{
    __shared__ __align__(16) float As[16][68];
    __shared__ __align__(16) float Bs[16][68];
    const int t  = threadIdx.x;
    const int tx = t & 15, ty = t >> 4;
    const int m0 = blockIdx.y * 64, n0 = blockIdx.x * 64;
    const int arow = t >> 2, aq = t & 3;
    const int brow = t >> 4, bq4 = t & 15;

    float acc[4][4] = {};

    for (int k0 = 0; k0 < DMODEL; k0 += 16) {
        __syncthreads();
        float4 av = {0.f, 0.f, 0.f, 0.f};
        if (m0 + arow < M)
            av = *(const float4*)&X[(size_t)(m0 + arow) * DMODEL + k0 + aq * 4];
        As[aq * 4 + 0][arow] = av.x;
        As[aq * 4 + 1][arow] = av.y;
        As[aq * 4 + 2][arow] = av.z;
        As[aq * 4 + 3][arow] = av.w;
        float4 bv = *(const float4*)&W[(size_t)(k0 + brow) * DMODEL + n0 + bq4 * 4];
        *(float4*)&Bs[brow][bq4 * 4] = bv;
        __syncthreads();

#pragma unroll
        for (int kk = 0; kk < 16; ++kk) {
            float4 a = *(const float4*)&As[kk][ty * 4];
            float4 b = *(const float4*)&Bs[kk][tx * 4];
            acc[0][0] += a.x * b.x; acc[0][1] += a.x * b.y; acc[0][2] += a.x * b.z; acc[0][3] += a.x * b.w;
            acc[1][0] += a.y * b.x; acc[1][1] += a.y * b.y; acc[1][2] += a.y * b.z; acc[1][3] += a.y * b.w;
            acc[2][0] += a.z * b.x; acc[2][1] += a.z * b.y; acc[2][2] += a.z * b.z; acc[2][3] += a.z * b.w;
            acc[3][0] += a.w * b.x; acc[3][1] += a.w * b.y; acc[3][2] += a.w * b.z; acc[3][3] += a.w * b.w;
        }
    }

    float4 b4 = *(const float4*)&bias[n0 + tx * 4];
#pragma unroll
    for (int i = 0; i < 4; ++i) {
        int m = m0 + ty * 4 + i;
        if (m >= M) continue;
        float vals[4];
        vals[0] = acc[i][0] + b4.x; vals[1] = acc[i][1] + b4.y;
        vals[2] = acc[i][2] + b4.z; vals[3] = acc[i][3] + b4.w;
        if (MODE == 1) {
            float4 o = {vals[0], vals[1], vals[2], vals[3]};
            *(float4*)&out32[(size_t)m * DMODEL + n0 + tx * 4] = o;
        } else {
            const int bb = m / rows, s = m - bb * rows;
            const int h  = n0 >> 6;
#pragma unroll
            for (int e = 0; e < 4; ++e) {
                float val = vals[e];
                __bf16 hb = (__bf16)val;
                __bf16 lb = (__bf16)(val - (float)hb);
                if (MODE == 0) {
                    size_t idx = (((size_t)(bb * HN + h) * SEQ + s) << 6) + tx * 4 + e;
                    outHi[idx] = hb; outLo[idx] = lb;
                } else { // MODE 2: transposed, padded key dim 1024
                    size_t idx = ((size_t)(bb * HN + h) * DH + tx * 4 + e) * 1024 + s;
                    outHi[idx] = hb; outLo[idx] = lb;
                }
            }
        }
    }
}

// ---------------------------------------------------------------
// QK^T via MFMA bf16 hi/lo split. Block: 64 rows x 64 cols, 4 waves
// (wave w = rows 16w..16w+15, all 64 cols). Writes masked relu'd
// logits (fp32) to att region.
// ---------------------------------------------------------------
__global__ __launch_bounds__(256)
void qk_mfma_kernel(const __bf16* __restrict__ qhi, const __bf16* __restrict__ qlo,
                    const __bf16* __restrict__ khi, const __bf16* __restrict__ klo,
                    const int* __restrict__ mask, float* __restrict__ att)
{
    const int bh = blockIdx.z, b = bh >> 4;
    const int w  = threadIdx.x >> 6, l = threadIdx.x & 63;
    const int lr = l & 15, ls = l >> 4;

    // A fragments (Q): row lr of this wave's 16-row tile, q row = att row + 1
    const int r_a  = blockIdx.y * 64 + w * 16 + lr;
    const int qrow = (r_a < SM1 ? r_a : SM1 - 1) + 1;   // <= 1023, in range
    const size_t qbase = ((size_t)bh * SEQ + qrow) * DH + ls * 8;
    const bf16x8 a0h = *(const bf16x8*)&qhi[qbase];
    const bf16x8 a0l = *(const bf16x8*)&qlo[qbase];
    const bf16x8 a1h = *(const bf16x8*)&qhi[qbase + 32];
    const bf16x8 a1l = *(const bf16x8*)&qlo[qbase + 32];

    const int orow0 = blockIdx.y * 64 + w * 16 + ls * 4;  // C/D rows

#pragma unroll
    for (int ct = 0; ct < 4; ++ct) {
        const int c    = blockIdx.x * 64 + ct * 16 + lr;
        const int krow = (c < SM1) ? c : SM1 - 1;
        const size_t kbase = ((size_t)bh * SEQ + krow) * DH + ls * 8;
        const bf16x8 b0h = *(const bf16x8*)&khi[kbase];
        const bf16x8 b0l = *(const bf16x8*)&klo[kbase];
        const bf16x8 b1h = *(const bf16x8*)&khi[kbase + 32];
        const bf16x8 b1l = *(const bf16x8*)&klo[kbase + 32];

        f32x4 acc = {0.f, 0.f, 0.f, 0.f};
        acc = __builtin_amdgcn_mfma_f32_16x16x32_bf16(a0h, b0h, acc, 0, 0, 0);
        acc = __builtin_amdgcn_mfma_f32_16x16x32_bf16(a0l, b0h, acc, 0, 0, 0);
        acc = __builtin_amdgcn_mfma_f32_16x16x32_bf16(a0h, b0l, acc, 0, 0, 0);
        acc = __builtin_amdgcn_mfma_f32_16x16x32_bf16(a1h, b1h, acc, 0, 0, 0);
        acc = __builtin_amdgcn_mfma_f32_16x16x32_bf16(a1l, b1h, acc, 0, 0, 0);
        acc = __builtin_amdgcn_mfma_f32_16x16x32_bf16(a1h, b1l, acc, 0, 0, 0);

        if (c < SM1) {
#pragma unroll
            for (int j = 0; j < 4; ++j) {
                const int r = orow0 + j;
                if (r < SM1) {
                    float sc = fmaxf(acc[j] * 0.125f, 0.f);
                    if (mask[((size_t)b * SM1 + r) * SM1 + c]) sc -= 1e9f;
                    att[((size_t)bh * SM1 + r) * SM1 + c] = sc;
                }
            }
        }
    }
}

// ---------------------------------------------------------------
// Row softmax in-place over att (fp32). Wave per row.
// ---------------------------------------------------------------
__global__ __launch_bounds__(256)
void softmax_kernel(float* __restrict__ att)
{
    const int row = blockIdx.x * 4 + (threadIdx.x >> 6);  // 0..32735 exact
    const int l   = threadIdx.x & 63;
    float* p = att + (size_t)row * SM1;

    float v[16];
    float m = -1e30f;
#pragma unroll
    for (int j = 0; j < 16; ++j) {
        const int c = l + 64 * j;
        v[j] = (c < SM1) ? p[c] : -1e30f;
        m = fmaxf(m, v[j]);
    }
#pragma unroll
    for (int off = 32; off; off >>= 1) m = fmaxf(m, __shfl_xor(m, off, 64));

    float sum = 0.f;
#pragma unroll
    for (int j = 0; j < 16; ++j) {
        v[j] = expf(v[j] - m);   // exp(-1e30 - m) == 0 for pad lanes
        sum += v[j];
    }
#pragma unroll
    for (int off = 32; off; off >>= 1) sum += __shfl_xor(sum, off, 64);

    const float inv = 1.0f / sum;
#pragma unroll
    for (int j = 0; j < 16; ++j) {
        const int c = l + 64 * j;
        if (c < SM1) p[c] = v[j] * inv;
    }
}

// ---------------------------------------------------------------
// PV via MFMA: ctx[b][r][h*64+dh] = sum_k W[r][k] * V[k][dh].
// W read fp32 from att (split in-kernel); V from padded bf16 planes.
// Block: 64 rows x 64 dh, 4 waves (wave = 16 rows x 64 dh).
// ---------------------------------------------------------------
__global__ __launch_bounds__(256)
void pv_mfma_kernel(const float* __restrict__ att, const __bf16* __restrict__ vthi,
                    const __bf16* __restrict__ vtlo, float* __restrict__ ctx)
{
    const int bh = blockIdx.y, b = bh >> 4, h = bh & 15;
    const int w  = threadIdx.x >> 6, l = threadIdx.x & 63;
    const int lr = l & 15, ls = l >> 4;

    const int wr  = blockIdx.x * 64 + w * 16 + lr;
    const int wrc = (wr < SM1) ? wr : SM1 - 1;
    const float* wrow = att + (size_t)bh * SM1 * SM1 + (size_t)wrc * SM1;

    f32x4 acc[4];
#pragma unroll
    for (int ct = 0; ct < 4; ++ct) acc[ct] = f32x4{0.f, 0.f, 0.f, 0.f};

    for (int kt = 0; kt < 32; ++kt) {
        const int kb = kt * 32 + ls * 8;
        float wv[8];
#pragma unroll
        for (int e = 0; e < 8; ++e) {
            const int kk = kb + e;
            wv[e] = (kk < SM1) ? wrow[kk] : 0.f;
        }
        bf16x8 ah, al;
#pragma unroll
        for (int e = 0; e < 8; ++e) {
            const __bf16 hb = (__bf16)wv[e];
            ah[e] = hb;
            al[e] = (__bf16)(wv[e] - (float)hb);
        }
#pragma unroll
        for (int ct = 0; ct < 4; ++ct) {
            const size_t vb = ((size_t)bh * DH + ct * 16 + lr) * 1024 + (size_t)kb;
            const bf16x8 vh8 = *(const bf16x8*)&vthi[vb];
            const bf16x8 vl8 = *(const bf16x8*)&vtlo[vb];
            acc[ct] = __builtin_amdgcn_mfma_f32_16x16x32_bf16(ah, vh8, acc[ct], 0, 0, 0);
            acc[ct] = __builtin_amdgcn_mfma_f32_16x16x32_bf16(al, vh8, acc[ct], 0, 0, 0);
            acc[ct] = __builtin_amdgcn_mfma_f32_16x16x32_bf16(ah, vl8, acc[ct], 0, 0, 0);
        }
    }

    const int orow0 = blockIdx.x * 64 + w * 16 + ls * 4;
#pragma unroll
    for (int ct = 0; ct < 4; ++ct) {
#pragma unroll
        for (int j = 0; j < 4; ++j) {
            const int r = orow0 + j;
            if (r < SM1)
                ctx[((size_t)b * SM1 + r) * DMODEL + h * DH + ct * 16 + lr] = acc[ct][j];
        }
    }
}

// ---------------------------------------------------------------
extern "C" void kernel_launch(void* const* d_in, const int* in_sizes, int n_in,
                              void* d_out, int out_size, void* d_ws, size_t ws_size,
                              hipStream_t stream) {
    const float* q    = (const float*)d_in[0];
    const float* k    = (const float*)d_in[1];
    const float* v    = (const float*)d_in[2];
    const int*   mask = (const int*)  d_in[4];
    const float* Wq   = (const float*)d_in[5];
    const float* bq   = (const float*)d_in[6];
    const float* Wk   = (const float*)d_in[7];
    const float* bk   = (const float*)d_in[8];
    const float* Wv   = (const float*)d_in[9];
    const float* bv   = (const float*)d_in[10];
    const float* Wo   = (const float*)d_in[11];
    const float* bo   = (const float*)d_in[12];

    float* out0 = (float*)d_out;                       // [2,1023,1024]
    float* att  = out0 + (size_t)2 * SM1 * DMODEL;     // [2,16,1023,1023]

    const size_t NQ  = (size_t)2 * HN * SEQ * DH;      // 2,097,152 per plane
    const size_t NVT = (size_t)2 * HN * DH * 1024;     // 2,097,152 per plane
    __bf16* ws16 = (__bf16*)d_ws;
    __bf16* qhi  = ws16;
    __bf16* qlo  = qhi + NQ;
    __bf16* khi  = qlo + NQ;
    __bf16* klo  = khi + NQ;
    __bf16* vthi = klo + NQ;
    __bf16* vtlo = vthi + NVT;
    float*  ctx  = (float*)(vtlo + NVT);               // [2,1023,1024]

    // zero V planes (padded key slot 1023 must be finite zero)
    hipMemsetAsync(vthi, 0, 2 * NVT * sizeof(__bf16), stream);

    gemm64_kernel<0><<<dim3(16, 32), 256, 0, stream>>>(q, Wq, bq, nullptr, qhi, qlo, 2 * SEQ, SEQ);
    gemm64_kernel<0><<<dim3(16, 32), 256, 0, stream>>>(k, Wk, bk, nullptr, khi, klo, 2 * SEQ, SEQ);
    gemm64_kernel<2><<<dim3(16, 32), 256, 0, stream>>>(v, Wv, bv, nullptr, vthi, vtlo, 2 * SM1, SM1);

    qk_mfma_kernel<<<dim3(16, 16, 32), 256, 0, stream>>>(qhi, qlo, khi, klo, mask, att);
    softmax_kernel<<<dim3(8184), 256, 0, stream>>>(att);
    pv_mfma_kernel<<<dim3(16, 32), 256, 0, stream>>>(att, vthi, vtlo, ctx);

    gemm64_kernel<1><<<dim3(16, 32), 256, 0, stream>>>(ctx, Wo, bo, out0, nullptr, nullptr, 2 * SM1, SM1);
}

// Round 4
// 353.505 us; speedup vs baseline: 14.9955x; 1.4584x over previous
//
#include <hip/hip_runtime.h>
#include <math.h>

#define HN 16
#define SEQ 1024
#define DMODEL 1024
#define DH 64
#define SM1 1023   // S-1

typedef float  f32x4  __attribute__((ext_vector_type(4)));
typedef __bf16 bf16x8 __attribute__((ext_vector_type(8)));

// ---------------------------------------------------------------
// MFMA GEMM with bf16 hi/lo split (3 MFMAs ~ fp32 precision).
// out = X[M x 1024] @ W[1024 x 1024] + bias
// MODE 0: head-split bf16 hi/lo planes out[bh][s(SEQ)][64]
// MODE 1: plain fp32 out[m][1024]
// MODE 2: transposed bf16 hi/lo planes out[bh][dh][1024(pad)]
// Tile 64x64, BK=32, 256 threads / 4 waves (wave = 16 rows x 64 cols).
// LDS: As/Bs [64][2 planes][32k] bf16, XOR-swizzled (^((row&7)<<4)).
// ---------------------------------------------------------------
template<int MODE>
__global__ __launch_bounds__(256)
void gemm_mfma_kernel(const float* __restrict__ X, const float* __restrict__ W,
                      const float* __restrict__ bias, float* __restrict__ out32,
                      __bf16* __restrict__ outHi, __bf16* __restrict__ outLo,
                      int M, int rows)
{
    __shared__ __align__(16) __bf16 As[4096];  // 8KB: row*128B + plane*64B + k*2B
    __shared__ __align__(16) __bf16 Bs[4096];  // 8KB: col*128B + plane*64B + k*2B

    const int t  = threadIdx.x;
    const int w  = t >> 6, l = t & 63;
    const int lr = l & 15, ls = l >> 4;
    const int m0 = blockIdx.y * 64, n0 = blockIdx.x * 64;
    const int sr  = t >> 2;       // staging row (A) / col (B), 0..63
    const int skq = t & 3;        // staging k-chunk (8 elems)

    f32x4 acc[4];
#pragma unroll
    for (int ct = 0; ct < 4; ++ct) acc[ct] = f32x4{0.f, 0.f, 0.f, 0.f};

    // precomputed fragment LDS byte addrs
    const int ar = w * 16 + lr;
    const int a_hi = (ar * 128 + ls * 16) ^ ((ar & 7) << 4);
    const int a_lo = (ar * 128 + 64 + ls * 16) ^ ((ar & 7) << 4);

    for (int k0 = 0; k0 < DMODEL; k0 += 32) {
        __syncthreads();
        // ---- stage A (64 rows x 32 k) ----
        {
            float xv[8];
            if (m0 + sr < M) {
                float4 v0 = *(const float4*)&X[(size_t)(m0 + sr) * DMODEL + k0 + skq * 8];
                float4 v1 = *(const float4*)&X[(size_t)(m0 + sr) * DMODEL + k0 + skq * 8 + 4];
                xv[0] = v0.x; xv[1] = v0.y; xv[2] = v0.z; xv[3] = v0.w;
                xv[4] = v1.x; xv[5] = v1.y; xv[6] = v1.z; xv[7] = v1.w;
            } else {
#pragma unroll
                for (int e = 0; e < 8; ++e) xv[e] = 0.f;
            }
            bf16x8 h8, l8;
#pragma unroll
            for (int e = 0; e < 8; ++e) {
                __bf16 hb = (__bf16)xv[e];
                h8[e] = hb;
                l8[e] = (__bf16)(xv[e] - (float)hb);
            }
            const int hiaddr = (sr * 128 + skq * 16) ^ ((sr & 7) << 4);
            const int loaddr = (sr * 128 + 64 + skq * 16) ^ ((sr & 7) << 4);
            *(bf16x8*)((char*)As + hiaddr) = h8;
            *(bf16x8*)((char*)As + loaddr) = l8;
        }
        // ---- stage B (32 k x 64 cols, stored [col][plane][k]) ----
        {
            float wv[8];
#pragma unroll
            for (int e = 0; e < 8; ++e)
                wv[e] = W[(size_t)(k0 + skq * 8 + e) * DMODEL + n0 + sr];
            bf16x8 h8, l8;
#pragma unroll
            for (int e = 0; e < 8; ++e) {
                __bf16 hb = (__bf16)wv[e];
                h8[e] = hb;
                l8[e] = (__bf16)(wv[e] - (float)hb);
            }
            const int hiaddr = (sr * 128 + skq * 16) ^ ((sr & 7) << 4);
            const int loaddr = (sr * 128 + 64 + skq * 16) ^ ((sr & 7) << 4);
            *(bf16x8*)((char*)Bs + hiaddr) = h8;
            *(bf16x8*)((char*)Bs + loaddr) = l8;
        }
        __syncthreads();

        // ---- fragments + MFMA ----
        const bf16x8 ah = *(const bf16x8*)((const char*)As + a_hi);
        const bf16x8 al = *(const bf16x8*)((const char*)As + a_lo);
#pragma unroll
        for (int ct = 0; ct < 4; ++ct) {
            const int bc = ct * 16 + lr;
            const int b_hi = (bc * 128 + ls * 16) ^ ((bc & 7) << 4);
            const int b_lo = (bc * 128 + 64 + ls * 16) ^ ((bc & 7) << 4);
            const bf16x8 bh = *(const bf16x8*)((const char*)Bs + b_hi);
            const bf16x8 bl = *(const bf16x8*)((const char*)Bs + b_lo);
            acc[ct] = __builtin_amdgcn_mfma_f32_16x16x32_bf16(ah, bh, acc[ct], 0, 0, 0);
            acc[ct] = __builtin_amdgcn_mfma_f32_16x16x32_bf16(al, bh, acc[ct], 0, 0, 0);
            acc[ct] = __builtin_amdgcn_mfma_f32_16x16x32_bf16(ah, bl, acc[ct], 0, 0, 0);
        }
    }

    // ---- epilogue ----
#pragma unroll
    for (int ct = 0; ct < 4; ++ct) {
        const int n = n0 + ct * 16 + lr;
        const float bv = bias[n];
#pragma unroll
        for (int j = 0; j < 4; ++j) {
            const int m = m0 + w * 16 + ls * 4 + j;
            if (m >= M) continue;
            const float val = acc[ct][j] + bv;
            if (MODE == 1) {
                out32[(size_t)m * DMODEL + n] = val;
            } else {
                const int bb = m / rows, s = m - bb * rows;
                const __bf16 hb = (__bf16)val;
                const __bf16 lb = (__bf16)(val - (float)hb);
                size_t idx;
                if (MODE == 0)
                    idx = (((size_t)(bb * HN + (n >> 6)) * SEQ + s) << 6) + (n & 63);
                else // MODE 2
                    idx = (((size_t)(bb * HN + (n >> 6)) * DH + (n & 63)) << 10) + s;
                outHi[idx] = hb; outLo[idx] = lb;
            }
        }
    }
}

// ---------------------------------------------------------------
// QK^T via MFMA bf16 hi/lo split. Block: 64 rows x 64 cols, 4 waves.
// ---------------------------------------------------------------
__global__ __launch_bounds__(256)
void qk_mfma_kernel(const __bf16* __restrict__ qhi, const __bf16* __restrict__ qlo,
                    const __bf16* __restrict__ khi, const __bf16* __restrict__ klo,
                    const int* __restrict__ mask, float* __restrict__ att)
{
    const int bh = blockIdx.z, b = bh >> 4;
    const int w  = threadIdx.x >> 6, l = threadIdx.x & 63;
    const int lr = l & 15, ls = l >> 4;

    const int r_a  = blockIdx.y * 64 + w * 16 + lr;
    const int qrow = (r_a < SM1 ? r_a : SM1 - 1) + 1;
    const size_t qbase = ((size_t)bh * SEQ + qrow) * DH + ls * 8;
    const bf16x8 a0h = *(const bf16x8*)&qhi[qbase];
    const bf16x8 a0l = *(const bf16x8*)&qlo[qbase];
    const bf16x8 a1h = *(const bf16x8*)&qhi[qbase + 32];
    const bf16x8 a1l = *(const bf16x8*)&qlo[qbase + 32];

    const int orow0 = blockIdx.y * 64 + w * 16 + ls * 4;

#pragma unroll
    for (int ct = 0; ct < 4; ++ct) {
        const int c    = blockIdx.x * 64 + ct * 16 + lr;
        const int krow = (c < SM1) ? c : SM1 - 1;
        const size_t kbase = ((size_t)bh * SEQ + krow) * DH + ls * 8;
        const bf16x8 b0h = *(const bf16x8*)&khi[kbase];
        const bf16x8 b0l = *(const bf16x8*)&klo[kbase];
        const bf16x8 b1h = *(const bf16x8*)&khi[kbase + 32];
        const bf16x8 b1l = *(const bf16x8*)&klo[kbase + 32];

        f32x4 acc = {0.f, 0.f, 0.f, 0.f};
        acc = __builtin_amdgcn_mfma_f32_16x16x32_bf16(a0h, b0h, acc, 0, 0, 0);
        acc = __builtin_amdgcn_mfma_f32_16x16x32_bf16(a0l, b0h, acc, 0, 0, 0);
        acc = __builtin_amdgcn_mfma_f32_16x16x32_bf16(a0h, b0l, acc, 0, 0, 0);
        acc = __builtin_amdgcn_mfma_f32_16x16x32_bf16(a1h, b1h, acc, 0, 0, 0);
        acc = __builtin_amdgcn_mfma_f32_16x16x32_bf16(a1l, b1h, acc, 0, 0, 0);
        acc = __builtin_amdgcn_mfma_f32_16x16x32_bf16(a1h, b1l, acc, 0, 0, 0);

        if (c < SM1) {
#pragma unroll
            for (int j = 0; j < 4; ++j) {
                const int r = orow0 + j;
                if (r < SM1) {
                    float sc = fmaxf(acc[j] * 0.125f, 0.f);
                    if (mask[((size_t)b * SM1 + r) * SM1 + c]) sc -= 1e9f;
                    att[((size_t)bh * SM1 + r) * SM1 + c] = sc;
                }
            }
        }
    }
}

// ---------------------------------------------------------------
// Row softmax in-place over att (fp32). Wave per row.
// ---------------------------------------------------------------
__global__ __launch_bounds__(256)
void softmax_kernel(float* __restrict__ att)
{
    const int row = blockIdx.x * 4 + (threadIdx.x >> 6);
    const int l   = threadIdx.x & 63;
    float* p = att + (size_t)row * SM1;

    float v[16];
    float m = -1e30f;
#pragma unroll
    for (int j = 0; j < 16; ++j) {
        const int c = l + 64 * j;
        v[j] = (c < SM1) ? p[c] : -1e30f;
        m = fmaxf(m, v[j]);
    }
#pragma unroll
    for (int off = 32; off; off >>= 1) m = fmaxf(m, __shfl_xor(m, off, 64));

    float sum = 0.f;
#pragma unroll
    for (int j = 0; j < 16; ++j) {
        v[j] = expf(v[j] - m);
        sum += v[j];
    }
#pragma unroll
    for (int off = 32; off; off >>= 1) sum += __shfl_xor(sum, off, 64);

    const float inv = 1.0f / sum;
#pragma unroll
    for (int j = 0; j < 16; ++j) {
        const int c = l + 64 * j;
        if (c < SM1) p[c] = v[j] * inv;
    }
}

// ---------------------------------------------------------------
// PV via MFMA hi/lo. Block: 64 rows x 64 dh, 4 waves.
// ---------------------------------------------------------------
__global__ __launch_bounds__(256)
void pv_mfma_kernel(const float* __restrict__ att, const __bf16* __restrict__ vthi,
                    const __bf16* __restrict__ vtlo, float* __restrict__ ctx)
{
    const int bh = blockIdx.y, b = bh >> 4, h = bh & 15;
    const int w  = threadIdx.x >> 6, l = threadIdx.x & 63;
    const int lr = l & 15, ls = l >> 4;

    const int wr  = blockIdx.x * 64 + w * 16 + lr;
    const int wrc = (wr < SM1) ? wr : SM1 - 1;
    const float* wrow = att + (size_t)bh * SM1 * SM1 + (size_t)wrc * SM1;

    f32x4 acc[4];
#pragma unroll
    for (int ct = 0; ct < 4; ++ct) acc[ct] = f32x4{0.f, 0.f, 0.f, 0.f};

    for (int kt = 0; kt < 32; ++kt) {
        const int kb = kt * 32 + ls * 8;
        float wv[8];
#pragma unroll
        for (int e = 0; e < 8; ++e) {
            const int kk = kb + e;
            wv[e] = (kk < SM1) ? wrow[kk] : 0.f;
        }
        bf16x8 ah, al;
#pragma unroll
        for (int e = 0; e < 8; ++e) {
            const __bf16 hb = (__bf16)wv[e];
            ah[e] = hb;
            al[e] = (__bf16)(wv[e] - (float)hb);
        }
#pragma unroll
        for (int ct = 0; ct < 4; ++ct) {
            const size_t vb = ((size_t)bh * DH + ct * 16 + lr) * 1024 + (size_t)kb;
            const bf16x8 vh8 = *(const bf16x8*)&vthi[vb];
            const bf16x8 vl8 = *(const bf16x8*)&vtlo[vb];
            acc[ct] = __builtin_amdgcn_mfma_f32_16x16x32_bf16(ah, vh8, acc[ct], 0, 0, 0);
            acc[ct] = __builtin_amdgcn_mfma_f32_16x16x32_bf16(al, vh8, acc[ct], 0, 0, 0);
            acc[ct] = __builtin_amdgcn_mfma_f32_16x16x32_bf16(ah, vl8, acc[ct], 0, 0, 0);
        }
    }

    const int orow0 = blockIdx.x * 64 + w * 16 + ls * 4;
#pragma unroll
    for (int ct = 0; ct < 4; ++ct) {
#pragma unroll
        for (int j = 0; j < 4; ++j) {
            const int r = orow0 + j;
            if (r < SM1)
                ctx[((size_t)b * SM1 + r) * DMODEL + h * DH + ct * 16 + lr] = acc[ct][j];
        }
    }
}

// ---------------------------------------------------------------
extern "C" void kernel_launch(void* const* d_in, const int* in_sizes, int n_in,
                              void* d_out, int out_size, void* d_ws, size_t ws_size,
                              hipStream_t stream) {
    const float* q    = (const float*)d_in[0];
    const float* k    = (const float*)d_in[1];
    const float* v    = (const float*)d_in[2];
    const int*   mask = (const int*)  d_in[4];
    const float* Wq   = (const float*)d_in[5];
    const float* bq   = (const float*)d_in[6];
    const float* Wk   = (const float*)d_in[7];
    const float* bk   = (const float*)d_in[8];
    const float* Wv   = (const float*)d_in[9];
    const float* bv   = (const float*)d_in[10];
    const float* Wo   = (const float*)d_in[11];
    const float* bo   = (const float*)d_in[12];

    float* out0 = (float*)d_out;                       // [2,1023,1024]
    float* att  = out0 + (size_t)2 * SM1 * DMODEL;     // [2,16,1023,1023]

    const size_t NQ  = (size_t)2 * HN * SEQ * DH;      // 2,097,152 per plane
    const size_t NVT = (size_t)2 * HN * DH * 1024;     // 2,097,152 per plane
    __bf16* ws16 = (__bf16*)d_ws;
    __bf16* qhi  = ws16;
    __bf16* qlo  = qhi + NQ;
    __bf16* khi  = qlo + NQ;
    __bf16* klo  = khi + NQ;
    __bf16* vthi = klo + NQ;
    __bf16* vtlo = vthi + NVT;
    float*  ctx  = (float*)(vtlo + NVT);               // [2,1023,1024]

    // zero V planes (padded key slot 1023 must be finite zero)
    hipMemsetAsync(vthi, 0, 2 * NVT * sizeof(__bf16), stream);

    gemm_mfma_kernel<0><<<dim3(16, 32), 256, 0, stream>>>(q, Wq, bq, nullptr, qhi, qlo, 2 * SEQ, SEQ);
    gemm_mfma_kernel<0><<<dim3(16, 32), 256, 0, stream>>>(k, Wk, bk, nullptr, khi, klo, 2 * SEQ, SEQ);
    gemm_mfma_kernel<2><<<dim3(16, 32), 256, 0, stream>>>(v, Wv, bv, nullptr, vthi, vtlo, 2 * SM1, SM1);

    qk_mfma_kernel<<<dim3(16, 16, 32), 256, 0, stream>>>(qhi, qlo, khi, klo, mask, att);
    softmax_kernel<<<dim3(8184), 256, 0, stream>>>(att);
    pv_mfma_kernel<<<dim3(16, 32), 256, 0, stream>>>(att, vthi, vtlo, ctx);

    gemm_mfma_kernel<1><<<dim3(16, 32), 256, 0, stream>>>(ctx, Wo, bo, out0, nullptr, nullptr, 2 * SM1, SM1);
}